// Round 1
// baseline (1109.406 us; speedup 1.0000x reference)
//
#include <hip/hip_runtime.h>

#define DECAY 0.99f
#define OMD   0.01f
#define EPS   1e-5f

constexpr int Bb = 16, Ss = 2048, Dd = 512, Kk = 2048;
constexpr int Nn = Bb * Ss;  // 32768

// ---------------- row sum-of-squares: out[row] = sum(in[row,:]^2) ----------
__global__ void rows_sq(const float* __restrict__ in, float* __restrict__ out, int nrows) {
    int row  = blockIdx.x * 4 + (threadIdx.x >> 6);
    int lane = threadIdx.x & 63;
    if (row >= nrows) return;
    const float4* p = (const float4*)(in + (size_t)row * Dd);
    float s = 0.f;
    #pragma unroll
    for (int i = 0; i < 2; ++i) {
        float4 v = p[lane + 64 * i];
        s += v.x * v.x + v.y * v.y + v.z * v.z + v.w * v.w;
    }
    #pragma unroll
    for (int off = 32; off; off >>= 1) s += __shfl_down(s, off);
    if (lane == 0) out[row] = s;
}

// ---------------- fp32 GEMM: dist[n,k] = 2*dot(x_n, e_k) - xsq[n] - esq[k] --
#define BM 64
#define BN 64
#define BK 32

__global__ __launch_bounds__(256) void gemm_dist(
    const float* __restrict__ A,    // x  [Nn, Dd]
    const float* __restrict__ Bm,   // embed [Kk, Dd]
    const float* __restrict__ xsq,
    const float* __restrict__ esq,
    float* __restrict__ dist)       // [Nn, Kk]
{
    __shared__ float As[BK][BM + 4];   // transposed: As[kd][row]
    __shared__ float Bs[BK][BN + 4];

    int tid  = threadIdx.x;
    int row0 = blockIdx.x * BM;   // over Nn
    int col0 = blockIdx.y * BN;   // over Kk
    int tx = tid & 15, ty = tid >> 4;

    float acc[4][4] = {};

    int lr = tid >> 3;        // 0..31
    int lc = (tid & 7) * 4;   // 0,4,..28

    for (int d0 = 0; d0 < Dd; d0 += BK) {
        float4 a0 = *(const float4*)(A  + (size_t)(row0 + lr)      * Dd + d0 + lc);
        float4 a1 = *(const float4*)(A  + (size_t)(row0 + lr + 32) * Dd + d0 + lc);
        float4 b0 = *(const float4*)(Bm + (size_t)(col0 + lr)      * Dd + d0 + lc);
        float4 b1 = *(const float4*)(Bm + (size_t)(col0 + lr + 32) * Dd + d0 + lc);
        __syncthreads();
        As[lc + 0][lr] = a0.x; As[lc + 1][lr] = a0.y; As[lc + 2][lr] = a0.z; As[lc + 3][lr] = a0.w;
        As[lc + 0][lr + 32] = a1.x; As[lc + 1][lr + 32] = a1.y; As[lc + 2][lr + 32] = a1.z; As[lc + 3][lr + 32] = a1.w;
        Bs[lc + 0][lr] = b0.x; Bs[lc + 1][lr] = b0.y; Bs[lc + 2][lr] = b0.z; Bs[lc + 3][lr] = b0.w;
        Bs[lc + 0][lr + 32] = b1.x; Bs[lc + 1][lr + 32] = b1.y; Bs[lc + 2][lr + 32] = b1.z; Bs[lc + 3][lr + 32] = b1.w;
        __syncthreads();
        #pragma unroll
        for (int kd = 0; kd < BK; ++kd) {
            float4 av = *(const float4*)&As[kd][ty * 4];
            float4 bv = *(const float4*)&Bs[kd][tx * 4];
            float a[4] = {av.x, av.y, av.z, av.w};
            float b[4] = {bv.x, bv.y, bv.z, bv.w};
            #pragma unroll
            for (int i = 0; i < 4; ++i)
                #pragma unroll
                for (int j = 0; j < 4; ++j)
                    acc[i][j] = fmaf(a[i], b[j], acc[i][j]);
        }
    }

    #pragma unroll
    for (int i = 0; i < 4; ++i) {
        int row = row0 + ty * 4 + i;
        float xs = xsq[row];
        float4 o;
        int col = col0 + tx * 4;
        o.x = 2.f * acc[i][0] - xs - esq[col + 0];
        o.y = 2.f * acc[i][1] - xs - esq[col + 1];
        o.z = 2.f * acc[i][2] - xs - esq[col + 2];
        o.w = 2.f * acc[i][3] - xs - esq[col + 3];
        *(float4*)(dist + (size_t)row * Kk + col) = o;
    }
}

// ---------------- per-row argmax over K (first-occurrence tie-break) -------
__global__ void argmax_k(const float* __restrict__ dist,
                         float* __restrict__ ind_f, int* __restrict__ ind_i) {
    int row  = blockIdx.x * 4 + (threadIdx.x >> 6);
    int lane = threadIdx.x & 63;
    const float4* p = (const float4*)(dist + (size_t)row * Kk);
    float best = -3.4e38f;
    int bidx = 0;
    #pragma unroll
    for (int it = 0; it < Kk / 4 / 64; ++it) {
        int i = lane + it * 64;
        float4 v = p[i];
        int base = i * 4;
        if (v.x > best) { best = v.x; bidx = base + 0; }
        if (v.y > best) { best = v.y; bidx = base + 1; }
        if (v.z > best) { best = v.z; bidx = base + 2; }
        if (v.w > best) { best = v.w; bidx = base + 3; }
    }
    #pragma unroll
    for (int off = 32; off; off >>= 1) {
        float ov = __shfl_down(best, off);
        int   oi = __shfl_down(bidx, off);
        if (ov > best || (ov == best && oi < bidx)) { best = ov; bidx = oi; }
    }
    if (lane == 0) { ind_f[row] = (float)bidx; ind_i[row] = bidx; }
}

// ---------------- quantize gather + segment-sum scatter --------------------
__global__ void gather_scatter(const float* __restrict__ x,
                               const float* __restrict__ embed,
                               const int* __restrict__ ind,
                               float* __restrict__ quant,
                               float* __restrict__ esum,
                               int* __restrict__ bins) {
    int n = blockIdx.x;
    int k = ind[n];
    int t = threadIdx.x;
    size_t xb = (size_t)n * Dd;
    size_t eb = (size_t)k * Dd;
    float v0 = x[xb + t];
    float v1 = x[xb + t + 256];
    quant[xb + t]       = embed[eb + t];
    quant[xb + t + 256] = embed[eb + t + 256];
    atomicAdd(&esum[eb + t],       v0);
    atomicAdd(&esum[eb + t + 256], v1);
    if (t == 0) atomicAdd(&bins[k], 1);
}

// ---------------- EMA cluster size + laplace total -------------------------
__global__ void finalize1(const float* __restrict__ cs, const int* __restrict__ bins,
                          float* __restrict__ ncs, float* __restrict__ total_ws) {
    __shared__ float red[16];
    int t = threadIdx.x;
    float s = 0.f;
    for (int k = t; k < Kk; k += 1024) {
        float v = cs[k] * DECAY + OMD * (float)bins[k];
        ncs[k] = v;
        s += v;
    }
    #pragma unroll
    for (int off = 32; off; off >>= 1) s += __shfl_down(s, off);
    if ((t & 63) == 0) red[t >> 6] = s;
    __syncthreads();
    if (t == 0) {
        float tot = 0.f;
        #pragma unroll
        for (int i = 0; i < 16; ++i) tot += red[i];
        total_ws[0] = tot;
    }
}

// ---------------- EMA embed_avg + smoothed divide ---------------------------
__global__ void finalize2(const float* __restrict__ ea, const float* __restrict__ esum,
                          const float* __restrict__ ncs, const float* __restrict__ total_ws,
                          float* __restrict__ nea, float* __restrict__ ne) {
    int idx = blockIdx.x * 256 + threadIdx.x;   // float4 index, K*D/4 total
    float total = total_ws[0];
    int k = idx >> 7;                            // idx / (Dd/4)
    float sm = (ncs[k] + EPS) / (total + Kk * EPS) * total;
    float inv = 1.f / sm;
    float4 a = ((const float4*)ea)[idx];
    float4 s = ((const float4*)esum)[idx];
    float4 r;
    r.x = a.x * DECAY + OMD * s.x;
    r.y = a.y * DECAY + OMD * s.y;
    r.z = a.z * DECAY + OMD * s.z;
    r.w = a.w * DECAY + OMD * s.w;
    ((float4*)nea)[idx] = r;
    float4 e;
    e.x = r.x * inv; e.y = r.y * inv; e.z = r.z * inv; e.w = r.w * inv;
    ((float4*)ne)[idx] = e;
}

extern "C" void kernel_launch(void* const* d_in, const int* in_sizes, int n_in,
                              void* d_out, int out_size, void* d_ws, size_t ws_size,
                              hipStream_t stream) {
    const float* x     = (const float*)d_in[0];
    const float* embed = (const float*)d_in[1];
    const float* cs    = (const float*)d_in[2];
    const float* ea    = (const float*)d_in[3];

    float* out     = (float*)d_out;
    float* o_quant = out;                          // 16777216
    float* o_ind   = o_quant + (size_t)Nn * Dd;    // 32768
    float* o_dist  = o_ind + Nn;                   // 67108864
    float* o_ncs   = o_dist + (size_t)Nn * Kk;     // 2048
    float* o_nea   = o_ncs + Kk;                   // 1048576
    float* o_ne    = o_nea + (size_t)Kk * Dd;      // 1048576

    float* xsq   = (float*)d_ws;                   // 32768
    float* esq   = xsq + Nn;                       // 2048
    int*   ind_i = (int*)(esq + Kk);               // 32768
    int*   bins  = ind_i + Nn;                     // 2048
    float* esum  = (float*)(bins + Kk);            // 1048576
    float* total = esum + (size_t)Kk * Dd;         // 1

    // zero the accumulators (bins + esum are adjacent)
    hipMemsetAsync(bins, 0, (size_t)(Kk + Kk * Dd) * sizeof(float), stream);

    rows_sq<<<Nn / 4, 256, 0, stream>>>(x, xsq, Nn);
    rows_sq<<<Kk / 4, 256, 0, stream>>>(embed, esq, Kk);

    dim3 g(Nn / BM, Kk / BN);
    gemm_dist<<<g, 256, 0, stream>>>(x, embed, xsq, esq, o_dist);

    argmax_k<<<Nn / 4, 256, 0, stream>>>(o_dist, o_ind, ind_i);

    gather_scatter<<<Nn, 256, 0, stream>>>(x, embed, ind_i, o_quant, esum, bins);

    finalize1<<<1, 1024, 0, stream>>>(cs, bins, o_ncs, total);
    finalize2<<<(Kk * Dd / 4) / 256, 256, 0, stream>>>(ea, esum, o_ncs, total, o_nea, o_ne);
}

// Round 2
// 740.713 us; speedup vs baseline: 1.4978x; 1.4978x over previous
//
#include <hip/hip_runtime.h>

#define DECAY 0.99f
#define OMD   0.01f
#define EPS   1e-5f

constexpr int Bb = 16, Ss = 2048, Dd = 512, Kk = 2048;
constexpr int Nn = Bb * Ss;  // 32768

typedef __attribute__((ext_vector_type(8))) short short8;
typedef __attribute__((ext_vector_type(4))) float f32x4;

__device__ __forceinline__ unsigned short f2bf(float x) {
    unsigned u = __float_as_uint(x);
    unsigned r = (u + 0x7FFFu + ((u >> 16) & 1u)) >> 16;   // RN-even
    return (unsigned short)r;
}
__device__ __forceinline__ float bf2f(unsigned short u) {
    return __uint_as_float((unsigned)u << 16);
}

__device__ __forceinline__ void gload_lds16(const void* g, void* l) {
    __builtin_amdgcn_global_load_lds(
        (const __attribute__((address_space(1))) void*)g,
        (__attribute__((address_space(3))) void*)l, 16, 0, 0);
}

// ---------------- row sum-of-squares ---------------------------------------
__global__ void rows_sq(const float* __restrict__ in, float* __restrict__ out, int nrows) {
    int row  = blockIdx.x * 4 + (threadIdx.x >> 6);
    int lane = threadIdx.x & 63;
    if (row >= nrows) return;
    const float4* p = (const float4*)(in + (size_t)row * Dd);
    float s = 0.f;
    #pragma unroll
    for (int i = 0; i < 2; ++i) {
        float4 v = p[lane + 64 * i];
        s += v.x * v.x + v.y * v.y + v.z * v.z + v.w * v.w;
    }
    #pragma unroll
    for (int off = 32; off; off >>= 1) s += __shfl_down(s, off);
    if (lane == 0) out[row] = s;
}

// ---------------- fp32 -> bf16x3 split -------------------------------------
__global__ void conv_split(const float* __restrict__ in,
                           unsigned short* __restrict__ ph,
                           unsigned short* __restrict__ pm,
                           unsigned short* __restrict__ pl, int n4) {
    int i = blockIdx.x * 256 + threadIdx.x;
    if (i >= n4) return;
    float4 v = ((const float4*)in)[i];
    float f[4] = {v.x, v.y, v.z, v.w};
    ushort4 h, m, l;
    unsigned short hh[4], mm[4], ll[4];
    #pragma unroll
    for (int j = 0; j < 4; ++j) {
        float x = f[j];
        unsigned short a = f2bf(x);  float ra = x - bf2f(a);
        unsigned short b = f2bf(ra); float rb = ra - bf2f(b);
        unsigned short c = f2bf(rb);
        hh[j] = a; mm[j] = b; ll[j] = c;
    }
    h.x = hh[0]; h.y = hh[1]; h.z = hh[2]; h.w = hh[3];
    m.x = mm[0]; m.y = mm[1]; m.z = mm[2]; m.w = mm[3];
    l.x = ll[0]; l.y = ll[1]; l.z = ll[2]; l.w = ll[3];
    ((ushort4*)ph)[i] = h;
    ((ushort4*)pm)[i] = m;
    ((ushort4*)pl)[i] = l;
}

// ---------------- bf16x3 MFMA GEMM: dist + fused argmax --------------------
// 128x128 tile, BK=64, K_eff = 6*512 = 3072, 4 waves (2x2), 16x16x32 MFMA.
__global__ __launch_bounds__(256) void gemm_split(
    const unsigned short* __restrict__ xp,   // [3][Nn][512] bf16 planes (h,m,l)
    const unsigned short* __restrict__ ep,   // [3][Kk][512]
    const float* __restrict__ xsq,
    const float* __restrict__ esq,
    float* __restrict__ dist,                // [Nn, Kk]
    unsigned long long* __restrict__ packed) // [Nn] argmax accumulator
{
    __shared__ unsigned short As[128][64];   // 16 KB, XOR-swizzled storage
    __shared__ unsigned short Bs[128][64];

    int tid  = threadIdx.x;
    int wid  = tid >> 6, lane = tid & 63;

    // XCD-aware swizzle: nwg = 4096 = 8*512
    int bid = blockIdx.x;
    int wg  = (bid & 7) * 512 + (bid >> 3);
    int mb  = wg >> 4, nb = wg & 15;
    int row0 = mb * 128, col0 = nb * 128;
    int wr = wid >> 1, wc = wid & 1;

    f32x4 acc[4][4] = {};

    // part-plane schedule for K_eff: (h,h)(h,m)(m,h)(m,m)(h,l)(l,h)
    const int APART[6] = {0, 0, 1, 1, 0, 2};
    const int BPART[6] = {0, 1, 0, 1, 2, 0};

    // staging geometry (per lane, constant across t)
    int srow[4], schk[4];
    #pragma unroll
    for (int it = 0; it < 4; ++it) {
        int r = it * 32 + wid * 8 + (lane >> 3);
        srow[it] = r;
        schk[it] = (lane & 7) ^ (r & 7);   // pre-swizzled source chunk
    }

    for (int t = 0; t < 48; ++t) {
        int p  = t >> 3;
        int ko = (t & 7) * 64;
        const unsigned short* Ap = xp + (size_t)APART[p] * Nn * Dd;
        const unsigned short* Bp = ep + (size_t)BPART[p] * Kk * Dd;

        __syncthreads();   // everyone done reading previous tile
        #pragma unroll
        for (int it = 0; it < 4; ++it) {
            const char* sa = (const char*)(Ap + (size_t)(row0 + srow[it]) * Dd + ko) + schk[it] * 16;
            const char* sb = (const char*)(Bp + (size_t)(col0 + srow[it]) * Dd + ko) + schk[it] * 16;
            gload_lds16(sa, &As[it * 32 + wid * 8][0]);
            gload_lds16(sb, &Bs[it * 32 + wid * 8][0]);
        }
        __syncthreads();   // staging drained (vmcnt(0) before barrier)

        #pragma unroll
        for (int kk = 0; kk < 2; ++kk) {
            short8 af[4], bfr[4];
            #pragma unroll
            for (int m = 0; m < 4; ++m) {
                int r = wr * 64 + m * 16 + (lane & 15);
                int c = (kk * 4 + (lane >> 4)) ^ (r & 7);   // swizzled read chunk
                af[m] = *(const short8*)&As[r][c * 8];
            }
            #pragma unroll
            for (int n = 0; n < 4; ++n) {
                int r = wc * 64 + n * 16 + (lane & 15);
                int c = (kk * 4 + (lane >> 4)) ^ (r & 7);
                bfr[n] = *(const short8*)&Bs[r][c * 8];
            }
            #pragma unroll
            for (int m = 0; m < 4; ++m)
                #pragma unroll
                for (int n = 0; n < 4; ++n)
                    acc[m][n] = __builtin_amdgcn_mfma_f32_16x16x32_bf16(af[m], bfr[n], acc[m][n], 0, 0, 0);
        }
    }

    // epilogue: dist = 2*dot - xsq - esq ; fused per-row argmax
    #pragma unroll
    for (int m = 0; m < 4; ++m) {
        #pragma unroll
        for (int j = 0; j < 4; ++j) {
            int row = row0 + wr * 64 + m * 16 + (lane >> 4) * 4 + j;
            float xs = xsq[row];
            float best = -3.4e38f; int bi = 0;
            #pragma unroll
            for (int n = 0; n < 4; ++n) {
                int col = col0 + wc * 64 + n * 16 + (lane & 15);
                float v = 2.f * acc[m][n][j] - xs - esq[col];
                dist[(size_t)row * Kk + col] = v;
                if (v > best) { best = v; bi = col; }
            }
            unsigned u = __float_as_uint(best);
            u = (u & 0x80000000u) ? ~u : (u | 0x80000000u);
            unsigned long long pk = ((unsigned long long)u << 32) | (unsigned)(~bi);
            #pragma unroll
            for (int off = 1; off < 16; off <<= 1) {
                unsigned long long o = __shfl_xor(pk, off);
                if (o > pk) pk = o;
            }
            if ((lane & 15) == 0) atomicMax(&packed[row], pk);
        }
    }
}

__global__ void unpack_argmax(const unsigned long long* __restrict__ packed,
                              float* __restrict__ ind_f, int* __restrict__ ind_i) {
    int i = blockIdx.x * 256 + threadIdx.x;
    unsigned long long p = packed[i];
    int k = (int)(~(unsigned)(p & 0xFFFFFFFFull));
    ind_f[i] = (float)k;
    ind_i[i] = k;
}

// ---------------- OLD fp32 GEMM (fallback when ws too small) ---------------
#define BM 64
#define BN 64
#define BK 32
__global__ __launch_bounds__(256) void gemm_dist(
    const float* __restrict__ A, const float* __restrict__ Bm,
    const float* __restrict__ xsq, const float* __restrict__ esq,
    float* __restrict__ dist)
{
    __shared__ float As[BK][BM + 4];
    __shared__ float Bs[BK][BN + 4];
    int tid = threadIdx.x;
    int row0 = blockIdx.x * BM, col0 = blockIdx.y * BN;
    int tx = tid & 15, ty = tid >> 4;
    float acc[4][4] = {};
    int lr = tid >> 3, lc = (tid & 7) * 4;
    for (int d0 = 0; d0 < Dd; d0 += BK) {
        float4 a0 = *(const float4*)(A  + (size_t)(row0 + lr)      * Dd + d0 + lc);
        float4 a1 = *(const float4*)(A  + (size_t)(row0 + lr + 32) * Dd + d0 + lc);
        float4 b0 = *(const float4*)(Bm + (size_t)(col0 + lr)      * Dd + d0 + lc);
        float4 b1 = *(const float4*)(Bm + (size_t)(col0 + lr + 32) * Dd + d0 + lc);
        __syncthreads();
        As[lc + 0][lr] = a0.x; As[lc + 1][lr] = a0.y; As[lc + 2][lr] = a0.z; As[lc + 3][lr] = a0.w;
        As[lc + 0][lr + 32] = a1.x; As[lc + 1][lr + 32] = a1.y; As[lc + 2][lr + 32] = a1.z; As[lc + 3][lr + 32] = a1.w;
        Bs[lc + 0][lr] = b0.x; Bs[lc + 1][lr] = b0.y; Bs[lc + 2][lr] = b0.z; Bs[lc + 3][lr] = b0.w;
        Bs[lc + 0][lr + 32] = b1.x; Bs[lc + 1][lr + 32] = b1.y; Bs[lc + 2][lr + 32] = b1.z; Bs[lc + 3][lr + 32] = b1.w;
        __syncthreads();
        #pragma unroll
        for (int kd = 0; kd < BK; ++kd) {
            float4 av = *(const float4*)&As[kd][ty * 4];
            float4 bv = *(const float4*)&Bs[kd][tx * 4];
            float a[4] = {av.x, av.y, av.z, av.w};
            float b[4] = {bv.x, bv.y, bv.z, bv.w};
            #pragma unroll
            for (int i = 0; i < 4; ++i)
                #pragma unroll
                for (int j = 0; j < 4; ++j)
                    acc[i][j] = fmaf(a[i], b[j], acc[i][j]);
        }
    }
    #pragma unroll
    for (int i = 0; i < 4; ++i) {
        int row = row0 + ty * 4 + i;
        float xs = xsq[row];
        float4 o;
        int col = col0 + tx * 4;
        o.x = 2.f * acc[i][0] - xs - esq[col + 0];
        o.y = 2.f * acc[i][1] - xs - esq[col + 1];
        o.z = 2.f * acc[i][2] - xs - esq[col + 2];
        o.w = 2.f * acc[i][3] - xs - esq[col + 3];
        *(float4*)(dist + (size_t)row * Kk + col) = o;
    }
}

__global__ void argmax_k(const float* __restrict__ dist,
                         float* __restrict__ ind_f, int* __restrict__ ind_i) {
    int row  = blockIdx.x * 4 + (threadIdx.x >> 6);
    int lane = threadIdx.x & 63;
    const float4* p = (const float4*)(dist + (size_t)row * Kk);
    float best = -3.4e38f;
    int bidx = 0;
    #pragma unroll
    for (int it = 0; it < Kk / 4 / 64; ++it) {
        int i = lane + it * 64;
        float4 v = p[i];
        int base = i * 4;
        if (v.x > best) { best = v.x; bidx = base + 0; }
        if (v.y > best) { best = v.y; bidx = base + 1; }
        if (v.z > best) { best = v.z; bidx = base + 2; }
        if (v.w > best) { best = v.w; bidx = base + 3; }
    }
    #pragma unroll
    for (int off = 32; off; off >>= 1) {
        float ov = __shfl_down(best, off);
        int   oi = __shfl_down(bidx, off);
        if (ov > best || (ov == best && oi < bidx)) { best = ov; bidx = oi; }
    }
    if (lane == 0) { ind_f[row] = (float)bidx; ind_i[row] = bidx; }
}

// ---------------- quantize gather + segment-sum scatter --------------------
__global__ void gather_scatter(const float* __restrict__ x,
                               const float* __restrict__ embed,
                               const int* __restrict__ ind,
                               float* __restrict__ quant,
                               float* __restrict__ esum,
                               int* __restrict__ bins) {
    int n = blockIdx.x;
    int k = ind[n];
    int t = threadIdx.x;
    size_t xb = (size_t)n * Dd;
    size_t eb = (size_t)k * Dd;
    float v0 = x[xb + t];
    float v1 = x[xb + t + 256];
    quant[xb + t]       = embed[eb + t];
    quant[xb + t + 256] = embed[eb + t + 256];
    atomicAdd(&esum[eb + t],       v0);
    atomicAdd(&esum[eb + t + 256], v1);
    if (t == 0) atomicAdd(&bins[k], 1);
}

// ---------------- EMA cluster size + laplace total -------------------------
__global__ void finalize1(const float* __restrict__ cs, const int* __restrict__ bins,
                          float* __restrict__ ncs, float* __restrict__ total_ws) {
    __shared__ float red[16];
    int t = threadIdx.x;
    float s = 0.f;
    for (int k = t; k < Kk; k += 1024) {
        float v = cs[k] * DECAY + OMD * (float)bins[k];
        ncs[k] = v;
        s += v;
    }
    #pragma unroll
    for (int off = 32; off; off >>= 1) s += __shfl_down(s, off);
    if ((t & 63) == 0) red[t >> 6] = s;
    __syncthreads();
    if (t == 0) {
        float tot = 0.f;
        #pragma unroll
        for (int i = 0; i < 16; ++i) tot += red[i];
        total_ws[0] = tot;
    }
}

// ---------------- EMA embed_avg + smoothed divide ---------------------------
__global__ void finalize2(const float* __restrict__ ea, const float* __restrict__ esum,
                          const float* __restrict__ ncs, const float* __restrict__ total_ws,
                          float* __restrict__ nea, float* __restrict__ ne) {
    int idx = blockIdx.x * 256 + threadIdx.x;
    float total = total_ws[0];
    int k = idx >> 7;
    float sm = (ncs[k] + EPS) / (total + Kk * EPS) * total;
    float inv = 1.f / sm;
    float4 a = ((const float4*)ea)[idx];
    float4 s = ((const float4*)esum)[idx];
    float4 r;
    r.x = a.x * DECAY + OMD * s.x;
    r.y = a.y * DECAY + OMD * s.y;
    r.z = a.z * DECAY + OMD * s.z;
    r.w = a.w * DECAY + OMD * s.w;
    ((float4*)nea)[idx] = r;
    float4 e;
    e.x = r.x * inv; e.y = r.y * inv; e.z = r.z * inv; e.w = r.w * inv;
    ((float4*)ne)[idx] = e;
}

extern "C" void kernel_launch(void* const* d_in, const int* in_sizes, int n_in,
                              void* d_out, int out_size, void* d_ws, size_t ws_size,
                              hipStream_t stream) {
    const float* x     = (const float*)d_in[0];
    const float* embed = (const float*)d_in[1];
    const float* cs    = (const float*)d_in[2];
    const float* ea    = (const float*)d_in[3];

    float* out     = (float*)d_out;
    float* o_quant = out;
    float* o_ind   = o_quant + (size_t)Nn * Dd;
    float* o_dist  = o_ind + Nn;
    float* o_ncs   = o_dist + (size_t)Nn * Kk;
    float* o_nea   = o_ncs + Kk;
    float* o_ne    = o_nea + (size_t)Kk * Dd;

    // ---- new-path ws layout ----
    size_t xp_elems = (size_t)3 * Nn * Dd;       // bf16
    size_t ep_elems = (size_t)3 * Kk * Dd;
    char* w = (char*)d_ws;
    unsigned short* xp = (unsigned short*)w;                 w += xp_elems * 2;
    unsigned short* epp = (unsigned short*)w;                w += ep_elems * 2;
    float* xsq   = (float*)w;                                w += (size_t)Nn * 4;
    float* esq   = (float*)w;                                w += (size_t)Kk * 4;
    int*   ind_i = (int*)w;                                  w += (size_t)Nn * 4;
    int*   bins  = (int*)w;                                  w += (size_t)Kk * 4;
    float* esum  = (float*)w;                                w += (size_t)Kk * Dd * 4;
    unsigned long long* packed = (unsigned long long*)w;     w += (size_t)Nn * 8;
    float* total = (float*)w;                                w += 256;
    size_t need = (size_t)(w - (char*)d_ws);

    if (ws_size >= need) {
        // zero bins + esum + packed (contiguous)
        hipMemsetAsync(bins, 0, (size_t)Kk * 4 + (size_t)Kk * Dd * 4 + (size_t)Nn * 8, stream);

        rows_sq<<<Nn / 4, 256, 0, stream>>>(x, xsq, Nn);
        rows_sq<<<Kk / 4, 256, 0, stream>>>(embed, esq, Kk);

        conv_split<<<(Nn * Dd / 4 + 255) / 256, 256, 0, stream>>>(
            x, xp, xp + (size_t)Nn * Dd, xp + (size_t)2 * Nn * Dd, Nn * Dd / 4);
        conv_split<<<(Kk * Dd / 4 + 255) / 256, 256, 0, stream>>>(
            embed, epp, epp + (size_t)Kk * Dd, epp + (size_t)2 * Kk * Dd, Kk * Dd / 4);

        gemm_split<<<(Nn / 128) * (Kk / 128), 256, 0, stream>>>(
            xp, epp, xsq, esq, o_dist, packed);

        unpack_argmax<<<Nn / 256, 256, 0, stream>>>(packed, o_ind, ind_i);
    } else {
        // fallback: fp32 path (round-1 layout fits in small ws)
        float* fxsq  = (float*)d_ws;
        float* fesq  = fxsq + Nn;
        int*   find  = (int*)(fesq + Kk);
        int*   fbins = find + Nn;
        float* fesum = (float*)(fbins + Kk);
        float* ftot  = fesum + (size_t)Kk * Dd;
        xsq = fxsq; esq = fesq; ind_i = find; bins = fbins; esum = fesum; total = ftot;

        hipMemsetAsync(bins, 0, (size_t)(Kk + Kk * Dd) * sizeof(float), stream);
        rows_sq<<<Nn / 4, 256, 0, stream>>>(x, xsq, Nn);
        rows_sq<<<Kk / 4, 256, 0, stream>>>(embed, esq, Kk);
        dim3 g(Nn / BM, Kk / BN);
        gemm_dist<<<g, 256, 0, stream>>>(x, embed, xsq, esq, o_dist);
        argmax_k<<<Nn / 4, 256, 0, stream>>>(o_dist, o_ind, ind_i);
    }

    gather_scatter<<<Nn, 256, 0, stream>>>(x, embed, ind_i, o_quant, esum, bins);
    finalize1<<<1, 1024, 0, stream>>>(cs, bins, o_ncs, total);
    finalize2<<<(Kk * Dd / 4) / 256, 256, 0, stream>>>(ea, esum, o_ncs, total, o_nea, o_ne);
}

// Round 3
// 556.967 us; speedup vs baseline: 1.9919x; 1.3299x over previous
//
#include <hip/hip_runtime.h>

#define DECAY 0.99f
#define OMD   0.01f
#define EPS   1e-5f

constexpr int Bb = 16, Ss = 2048, Dd = 512, Kk = 2048;
constexpr int Nn = Bb * Ss;  // 32768

typedef __attribute__((ext_vector_type(8))) short short8;
typedef __attribute__((ext_vector_type(4))) float f32x4;

__device__ __forceinline__ unsigned short f2bf(float x) {
    unsigned u = __float_as_uint(x);
    unsigned r = (u + 0x7FFFu + ((u >> 16) & 1u)) >> 16;   // RN-even
    return (unsigned short)r;
}
__device__ __forceinline__ float bf2f(unsigned short u) {
    return __uint_as_float((unsigned)u << 16);
}

__device__ __forceinline__ void gload_lds16(const void* g, void* l) {
    __builtin_amdgcn_global_load_lds(
        (const __attribute__((address_space(1))) void*)g,
        (__attribute__((address_space(3))) void*)l, 16, 0, 0);
}

// ---------------- row sum-of-squares ---------------------------------------
__global__ void rows_sq(const float* __restrict__ in, float* __restrict__ out, int nrows) {
    int row  = blockIdx.x * 4 + (threadIdx.x >> 6);
    int lane = threadIdx.x & 63;
    if (row >= nrows) return;
    const float4* p = (const float4*)(in + (size_t)row * Dd);
    float s = 0.f;
    #pragma unroll
    for (int i = 0; i < 2; ++i) {
        float4 v = p[lane + 64 * i];
        s += v.x * v.x + v.y * v.y + v.z * v.z + v.w * v.w;
    }
    #pragma unroll
    for (int off = 32; off; off >>= 1) s += __shfl_down(s, off);
    if (lane == 0) out[row] = s;
}

// ---------------- fp32 -> bf16x3 split -------------------------------------
__global__ void conv_split(const float* __restrict__ in,
                           unsigned short* __restrict__ ph,
                           unsigned short* __restrict__ pm,
                           unsigned short* __restrict__ pl, int n4) {
    int i = blockIdx.x * 256 + threadIdx.x;
    if (i >= n4) return;
    float4 v = ((const float4*)in)[i];
    float f[4] = {v.x, v.y, v.z, v.w};
    ushort4 h, m, l;
    unsigned short hh[4], mm[4], ll[4];
    #pragma unroll
    for (int j = 0; j < 4; ++j) {
        float x = f[j];
        unsigned short a = f2bf(x);  float ra = x - bf2f(a);
        unsigned short b = f2bf(ra); float rb = ra - bf2f(b);
        unsigned short c = f2bf(rb);
        hh[j] = a; mm[j] = b; ll[j] = c;
    }
    h.x = hh[0]; h.y = hh[1]; h.z = hh[2]; h.w = hh[3];
    m.x = mm[0]; m.y = mm[1]; m.z = mm[2]; m.w = mm[3];
    l.x = ll[0]; l.y = ll[1]; l.z = ll[2]; l.w = ll[3];
    ((ushort4*)ph)[i] = h;
    ((ushort4*)pm)[i] = m;
    ((ushort4*)pl)[i] = l;
}

// ---------------- bf16x3 MFMA GEMM, 256x256 tile, 4-phase pipelined --------
// K_eff = 6*512 = 3072 -> 48 K-tiles of BK=64. 8 waves (2M x 4N), 512 thr.
// LDS 128 KB double-buffered. Counted-vmcnt schedule (derived, formally
// covering): per wave stages [A-lo, B-lo, A-hi, B-hi] (2 loads/phase) for
// tile t+1 during tile t; waits vmcnt(2)@ph0-end, vmcnt(4)@ph3-end.
__global__ __launch_bounds__(512, 1) void gemm_split256(
    const unsigned short* __restrict__ xp,   // [3][Nn][512] bf16 planes
    const unsigned short* __restrict__ ep,   // [3][Kk][512]
    const float* __restrict__ xsq,
    const float* __restrict__ esq,
    float* __restrict__ dist,                // [Nn, Kk]
    unsigned long long* __restrict__ packed) // [Nn] argmax accumulator
{
    __shared__ unsigned short As[2][256][64];   // 64 KB
    __shared__ unsigned short Bs[2][256][64];   // 64 KB

    const int tid  = threadIdx.x;
    const int lane = tid & 63;
    const int wid  = tid >> 6;
    const int wr   = wid >> 2;   // 0..1  (M direction, 128 rows each)
    const int wc   = wid & 3;    // 0..3  (N direction, 64 cols each)

    // XCD-aware swizzle (nwg = 1024, divisible by 8 -> bijective)
    int bid = blockIdx.x;
    int wg  = (bid & 7) * 128 + (bid >> 3);
    int mb  = wg >> 3, nb = wg & 7;
    const int row0 = mb * 256, col0 = nb * 256;

    f32x4 acc[8][4] = {};
    short8 af[4][2], bf[2][2];

    const int l8   = lane >> 3;   // 0..7
    const int c8   = lane & 7;
    const int csrc = c8 ^ l8;     // pre-swizzled source chunk

    auto planeA = [&](int tt) -> const unsigned short* {
        int p = tt >> 3;  // part schedule A: h,h,m,m,h,l
        int ap = (p == 2 || p == 3) ? 1 : ((p == 5) ? 2 : 0);
        return xp + (size_t)ap * ((size_t)Nn * Dd);
    };
    auto planeB = [&](int tt) -> const unsigned short* {
        int p = tt >> 3;  // part schedule B: h,m,h,m,l,h
        int bp = (p == 1 || p == 3) ? 1 : ((p == 4) ? 2 : 0);
        return ep + (size_t)bp * ((size_t)Kk * Dd);
    };

    auto stageA = [&](int bufi, int tt, int jj) {
        int ko = (tt & 7) * 64;
        int rowbase = wr * 128 + (jj & 2) * 32 + wc * 16 + (jj & 1) * 8;
        int ra = rowbase + l8;
        const unsigned short* src = planeA(tt) + (size_t)(row0 + ra) * Dd + ko + csrc * 8;
        gload_lds16(src, &As[bufi][rowbase][0]);
    };
    auto stageB = [&](int bufi, int tt, int jj) {
        int ko = (tt & 7) * 64;
        int rowbase = wc * 64 + (jj & 2) * 16 + wr * 16 + (jj & 1) * 8;
        int rb = rowbase + l8;
        const unsigned short* src = planeB(tt) + (size_t)(col0 + rb) * Dd + ko + csrc * 8;
        gload_lds16(src, &Bs[bufi][rowbase][0]);
    };

    auto readA4 = [&](int bufi, int msel) {
        #pragma unroll
        for (int m = 0; m < 4; ++m) {
            int r = wr * 128 + (msel * 4 + m) * 16 + (lane & 15);
            #pragma unroll
            for (int ks = 0; ks < 2; ++ks) {
                int c = (ks * 4 + (lane >> 4)) ^ (r & 7);
                af[m][ks] = *(const short8*)&As[bufi][r][c * 8];
            }
        }
    };
    auto readB2 = [&](int bufi, int nsel) {
        #pragma unroll
        for (int n = 0; n < 2; ++n) {
            int r = wc * 64 + (nsel * 2 + n) * 16 + (lane & 15);
            #pragma unroll
            for (int ks = 0; ks < 2; ++ks) {
                int c = (ks * 4 + (lane >> 4)) ^ (r & 7);
                bf[n][ks] = *(const short8*)&Bs[bufi][r][c * 8];
            }
        }
    };

    auto mfma16 = [&](int msel, int nsel) {
        __builtin_amdgcn_s_setprio(1);
        #pragma unroll
        for (int ks = 0; ks < 2; ++ks)
            #pragma unroll
            for (int m = 0; m < 4; ++m)
                #pragma unroll
                for (int n = 0; n < 2; ++n)
                    acc[msel * 4 + m][nsel * 2 + n] =
                        __builtin_amdgcn_mfma_f32_16x16x32_bf16(af[m][ks], bf[n][ks],
                            acc[msel * 4 + m][nsel * 2 + n], 0, 0, 0);
        __builtin_amdgcn_s_setprio(0);
    };

    // prologue: fully stage tile 0 into buf 0 (order: Alo, Blo, Ahi, Bhi)
    stageA(0, 0, 0); stageA(0, 0, 1);
    stageB(0, 0, 0); stageB(0, 0, 1);
    stageA(0, 0, 2); stageA(0, 0, 3);
    stageB(0, 0, 2); stageB(0, 0, 3);
    asm volatile("s_waitcnt vmcnt(4)" ::: "memory");   // Alo,Blo complete
    __builtin_amdgcn_s_barrier();

    for (int t = 0; t < 48; ++t) {
        const int cur = t & 1, nxt = cur ^ 1;
        const bool st = (t < 47);
        // ---- ph0: m0-3 x n0-1 ----
        readA4(cur, 0); readB2(cur, 0);
        if (st) { stageA(nxt, t + 1, 0); stageA(nxt, t + 1, 1); }
        __builtin_amdgcn_s_barrier();
        mfma16(0, 0);
        if (st) asm volatile("s_waitcnt vmcnt(2)" ::: "memory");  // Ahi,Bhi(t) done
        else    asm volatile("s_waitcnt vmcnt(0)" ::: "memory");
        __builtin_amdgcn_s_barrier();
        // ---- ph1: m0-3 x n2-3 ----
        readB2(cur, 1);
        if (st) { stageB(nxt, t + 1, 0); stageB(nxt, t + 1, 1); }
        __builtin_amdgcn_s_barrier();
        mfma16(0, 1);
        __builtin_amdgcn_s_barrier();
        // ---- ph2: m4-7 x n2-3 ----
        readA4(cur, 1);
        if (st) { stageA(nxt, t + 1, 2); stageA(nxt, t + 1, 3); }
        __builtin_amdgcn_s_barrier();
        mfma16(1, 1);
        __builtin_amdgcn_s_barrier();
        // ---- ph3: m4-7 x n0-1 (re-read B-lo) ----
        readB2(cur, 0);
        if (st) { stageB(nxt, t + 1, 2); stageB(nxt, t + 1, 3); }
        __builtin_amdgcn_s_barrier();
        mfma16(1, 0);
        if (st) asm volatile("s_waitcnt vmcnt(4)" ::: "memory");  // Alo,Blo(t+1) done
        __builtin_amdgcn_s_barrier();
    }

    // epilogue: dist = 2*dot - xsq - esq ; fused per-row argmax
    const int jrow = (lane >> 4) * 4;
    const int ncol = lane & 15;
    #pragma unroll
    for (int m = 0; m < 8; ++m) {
        int rbase = row0 + wr * 128 + m * 16 + jrow;
        #pragma unroll
        for (int j = 0; j < 4; ++j) {
            int row = rbase + j;
            float xs = xsq[row];
            float best = -3.4e38f; int bi = 0;
            #pragma unroll
            for (int n = 0; n < 4; ++n) {
                int col = col0 + wc * 64 + n * 16 + ncol;
                float v = 2.f * acc[m][n][j] - xs - esq[col];
                dist[(size_t)row * Kk + col] = v;
                if (v > best) { best = v; bi = col; }
            }
            unsigned u = __float_as_uint(best);
            u = (u & 0x80000000u) ? ~u : (u | 0x80000000u);
            unsigned long long pk = ((unsigned long long)u << 32) | (unsigned)(~bi);
            #pragma unroll
            for (int off = 1; off < 16; off <<= 1) {
                unsigned long long o = __shfl_xor(pk, off);
                if (o > pk) pk = o;
            }
            if (ncol == 0) atomicMax(&packed[row], pk);
        }
    }
}

__global__ void unpack_argmax(const unsigned long long* __restrict__ packed,
                              float* __restrict__ ind_f, int* __restrict__ ind_i) {
    int i = blockIdx.x * 256 + threadIdx.x;
    unsigned long long p = packed[i];
    int k = (int)(~(unsigned)(p & 0xFFFFFFFFull));
    ind_f[i] = (float)k;
    ind_i[i] = k;
}

// ---------------- OLD fp32 GEMM (fallback when ws too small) ---------------
#define BM 64
#define BN 64
#define BK 32
__global__ __launch_bounds__(256) void gemm_dist(
    const float* __restrict__ A, const float* __restrict__ Bm,
    const float* __restrict__ xsq, const float* __restrict__ esq,
    float* __restrict__ dist)
{
    __shared__ float Asl[BK][BM + 4];
    __shared__ float Bsl[BK][BN + 4];
    int tid = threadIdx.x;
    int row0 = blockIdx.x * BM, col0 = blockIdx.y * BN;
    int tx = tid & 15, ty = tid >> 4;
    float acc[4][4] = {};
    int lr = tid >> 3, lc = (tid & 7) * 4;
    for (int d0 = 0; d0 < Dd; d0 += BK) {
        float4 a0 = *(const float4*)(A  + (size_t)(row0 + lr)      * Dd + d0 + lc);
        float4 a1 = *(const float4*)(A  + (size_t)(row0 + lr + 32) * Dd + d0 + lc);
        float4 b0 = *(const float4*)(Bm + (size_t)(col0 + lr)      * Dd + d0 + lc);
        float4 b1 = *(const float4*)(Bm + (size_t)(col0 + lr + 32) * Dd + d0 + lc);
        __syncthreads();
        Asl[lc + 0][lr] = a0.x; Asl[lc + 1][lr] = a0.y; Asl[lc + 2][lr] = a0.z; Asl[lc + 3][lr] = a0.w;
        Asl[lc + 0][lr + 32] = a1.x; Asl[lc + 1][lr + 32] = a1.y; Asl[lc + 2][lr + 32] = a1.z; Asl[lc + 3][lr + 32] = a1.w;
        Bsl[lc + 0][lr] = b0.x; Bsl[lc + 1][lr] = b0.y; Bsl[lc + 2][lr] = b0.z; Bsl[lc + 3][lr] = b0.w;
        Bsl[lc + 0][lr + 32] = b1.x; Bsl[lc + 1][lr + 32] = b1.y; Bsl[lc + 2][lr + 32] = b1.z; Bsl[lc + 3][lr + 32] = b1.w;
        __syncthreads();
        #pragma unroll
        for (int kd = 0; kd < BK; ++kd) {
            float4 av = *(const float4*)&Asl[kd][ty * 4];
            float4 bv = *(const float4*)&Bsl[kd][tx * 4];
            float a[4] = {av.x, av.y, av.z, av.w};
            float b[4] = {bv.x, bv.y, bv.z, bv.w};
            #pragma unroll
            for (int i = 0; i < 4; ++i)
                #pragma unroll
                for (int j = 0; j < 4; ++j)
                    acc[i][j] = fmaf(a[i], b[j], acc[i][j]);
        }
    }
    #pragma unroll
    for (int i = 0; i < 4; ++i) {
        int row = row0 + ty * 4 + i;
        float xs = xsq[row];
        float4 o;
        int col = col0 + tx * 4;
        o.x = 2.f * acc[i][0] - xs - esq[col + 0];
        o.y = 2.f * acc[i][1] - xs - esq[col + 1];
        o.z = 2.f * acc[i][2] - xs - esq[col + 2];
        o.w = 2.f * acc[i][3] - xs - esq[col + 3];
        *(float4*)(dist + (size_t)row * Kk + col) = o;
    }
}

__global__ void argmax_k(const float* __restrict__ dist,
                         float* __restrict__ ind_f, int* __restrict__ ind_i) {
    int row  = blockIdx.x * 4 + (threadIdx.x >> 6);
    int lane = threadIdx.x & 63;
    const float4* p = (const float4*)(dist + (size_t)row * Kk);
    float best = -3.4e38f;
    int bidx = 0;
    #pragma unroll
    for (int it = 0; it < Kk / 4 / 64; ++it) {
        int i = lane + it * 64;
        float4 v = p[i];
        int base = i * 4;
        if (v.x > best) { best = v.x; bidx = base + 0; }
        if (v.y > best) { best = v.y; bidx = base + 1; }
        if (v.z > best) { best = v.z; bidx = base + 2; }
        if (v.w > best) { best = v.w; bidx = base + 3; }
    }
    #pragma unroll
    for (int off = 32; off; off >>= 1) {
        float ov = __shfl_down(best, off);
        int   oi = __shfl_down(bidx, off);
        if (ov > best || (ov == best && oi < bidx)) { best = ov; bidx = oi; }
    }
    if (lane == 0) { ind_f[row] = (float)bidx; ind_i[row] = bidx; }
}

// ---------------- quantize gather + segment-sum scatter --------------------
__global__ void gather_scatter(const float* __restrict__ x,
                               const float* __restrict__ embed,
                               const int* __restrict__ ind,
                               float* __restrict__ quant,
                               float* __restrict__ esum,
                               int* __restrict__ bins) {
    int n = blockIdx.x;
    int k = ind[n];
    int t = threadIdx.x;
    size_t xb = (size_t)n * Dd;
    size_t eb = (size_t)k * Dd;
    float v0 = x[xb + t];
    float v1 = x[xb + t + 256];
    quant[xb + t]       = embed[eb + t];
    quant[xb + t + 256] = embed[eb + t + 256];
    atomicAdd(&esum[eb + t],       v0);
    atomicAdd(&esum[eb + t + 256], v1);
    if (t == 0) atomicAdd(&bins[k], 1);
}

// ---------------- EMA cluster size + laplace total -------------------------
__global__ void finalize1(const float* __restrict__ cs, const int* __restrict__ bins,
                          float* __restrict__ ncs, float* __restrict__ total_ws) {
    __shared__ float red[16];
    int t = threadIdx.x;
    float s = 0.f;
    for (int k = t; k < Kk; k += 1024) {
        float v = cs[k] * DECAY + OMD * (float)bins[k];
        ncs[k] = v;
        s += v;
    }
    #pragma unroll
    for (int off = 32; off; off >>= 1) s += __shfl_down(s, off);
    if ((t & 63) == 0) red[t >> 6] = s;
    __syncthreads();
    if (t == 0) {
        float tot = 0.f;
        #pragma unroll
        for (int i = 0; i < 16; ++i) tot += red[i];
        total_ws[0] = tot;
    }
}

// ---------------- EMA embed_avg + smoothed divide ---------------------------
__global__ void finalize2(const float* __restrict__ ea, const float* __restrict__ esum,
                          const float* __restrict__ ncs, const float* __restrict__ total_ws,
                          float* __restrict__ nea, float* __restrict__ ne) {
    int idx = blockIdx.x * 256 + threadIdx.x;
    float total = total_ws[0];
    int k = idx >> 7;
    float sm = (ncs[k] + EPS) / (total + Kk * EPS) * total;
    float inv = 1.f / sm;
    float4 a = ((const float4*)ea)[idx];
    float4 s = ((const float4*)esum)[idx];
    float4 r;
    r.x = a.x * DECAY + OMD * s.x;
    r.y = a.y * DECAY + OMD * s.y;
    r.z = a.z * DECAY + OMD * s.z;
    r.w = a.w * DECAY + OMD * s.w;
    ((float4*)nea)[idx] = r;
    float4 e;
    e.x = r.x * inv; e.y = r.y * inv; e.z = r.z * inv; e.w = r.w * inv;
    ((float4*)ne)[idx] = e;
}

extern "C" void kernel_launch(void* const* d_in, const int* in_sizes, int n_in,
                              void* d_out, int out_size, void* d_ws, size_t ws_size,
                              hipStream_t stream) {
    const float* x     = (const float*)d_in[0];
    const float* embed = (const float*)d_in[1];
    const float* cs    = (const float*)d_in[2];
    const float* ea    = (const float*)d_in[3];

    float* out     = (float*)d_out;
    float* o_quant = out;
    float* o_ind   = o_quant + (size_t)Nn * Dd;
    float* o_dist  = o_ind + Nn;
    float* o_ncs   = o_dist + (size_t)Nn * Kk;
    float* o_nea   = o_ncs + Kk;
    float* o_ne    = o_nea + (size_t)Kk * Dd;

    // ---- ws layout ----
    size_t xp_elems = (size_t)3 * Nn * Dd;       // bf16
    size_t ep_elems = (size_t)3 * Kk * Dd;
    char* w = (char*)d_ws;
    unsigned short* xp = (unsigned short*)w;                 w += xp_elems * 2;
    unsigned short* epp = (unsigned short*)w;                w += ep_elems * 2;
    float* xsq   = (float*)w;                                w += (size_t)Nn * 4;
    float* esq   = (float*)w;                                w += (size_t)Kk * 4;
    int*   ind_i = (int*)w;                                  w += (size_t)Nn * 4;
    int*   bins  = (int*)w;                                  w += (size_t)Kk * 4;
    float* esum  = (float*)w;                                w += (size_t)Kk * Dd * 4;
    unsigned long long* packed = (unsigned long long*)w;     w += (size_t)Nn * 8;
    float* total = (float*)w;                                w += 256;
    size_t need = (size_t)(w - (char*)d_ws);

    if (ws_size >= need) {
        // zero bins + esum + packed (contiguous)
        hipMemsetAsync(bins, 0, (size_t)Kk * 4 + (size_t)Kk * Dd * 4 + (size_t)Nn * 8, stream);

        rows_sq<<<Nn / 4, 256, 0, stream>>>(x, xsq, Nn);
        rows_sq<<<Kk / 4, 256, 0, stream>>>(embed, esq, Kk);

        conv_split<<<(Nn * Dd / 4 + 255) / 256, 256, 0, stream>>>(
            x, xp, xp + (size_t)Nn * Dd, xp + (size_t)2 * Nn * Dd, Nn * Dd / 4);
        conv_split<<<(Kk * Dd / 4 + 255) / 256, 256, 0, stream>>>(
            embed, epp, epp + (size_t)Kk * Dd, epp + (size_t)2 * Kk * Dd, Kk * Dd / 4);

        gemm_split256<<<(Nn / 256) * (Kk / 256), 512, 0, stream>>>(
            xp, epp, xsq, esq, o_dist, packed);

        unpack_argmax<<<Nn / 256, 256, 0, stream>>>(packed, o_ind, ind_i);
    } else {
        // fallback: fp32 path
        float* fxsq  = (float*)d_ws;
        float* fesq  = fxsq + Nn;
        int*   find  = (int*)(fesq + Kk);
        int*   fbins = find + Nn;
        float* fesum = (float*)(fbins + Kk);
        float* ftot  = fesum + (size_t)Kk * Dd;
        xsq = fxsq; esq = fesq; ind_i = find; bins = fbins; esum = fesum; total = ftot;

        hipMemsetAsync(bins, 0, (size_t)(Kk + Kk * Dd) * sizeof(float), stream);
        rows_sq<<<Nn / 4, 256, 0, stream>>>(x, xsq, Nn);
        rows_sq<<<Kk / 4, 256, 0, stream>>>(embed, esq, Kk);
        dim3 g(Nn / BM, Kk / BN);
        gemm_dist<<<g, 256, 0, stream>>>(x, embed, xsq, esq, o_dist);
        argmax_k<<<Nn / 4, 256, 0, stream>>>(o_dist, o_ind, ind_i);
    }

    gather_scatter<<<Nn, 256, 0, stream>>>(x, embed, ind_i, o_quant, esum, bins);
    finalize1<<<1, 1024, 0, stream>>>(cs, bins, o_ncs, total);
    finalize2<<<(Kk * Dd / 4) / 256, 256, 0, stream>>>(ea, esum, o_ncs, total, o_nea, o_ne);
}